// Round 1
// baseline (1805.624 us; speedup 1.0000x reference)
//
#include <hip/hip_runtime.h>

// UnstructuredNetwork: out = proj( scan_{50}( h += dt*leaky(leaky(h@W1+b1)@W2+b2) )( lift(x) ) )
// B=2e6 samples, DIN=3, HID=20, NLAYERS=50, DOUT=3. fp32 throughout.
// Compute-bound: ~160 GFLOP vs ~48 MB HBM traffic. One thread per sample,
// h/t/u register-resident; weight indices are wave-uniform -> scalar loads.

#define DIN 3
#define HID 20
#define NLAYERS 50
#define DOUT 3
#define NEG_SLOPE 0.01f

__device__ __forceinline__ float leaky(float z) {
    return z >= 0.0f ? z : NEG_SLOPE * z;
}

__global__ __launch_bounds__(256) void unet_mlp_kernel(
    const float* __restrict__ x,
    const float* __restrict__ lift_w,   // [DIN][HID]
    const float* __restrict__ lift_b,   // [HID]
    const float* __restrict__ W1,       // [NLAYERS][HID][HID]
    const float* __restrict__ b1,       // [NLAYERS][HID]
    const float* __restrict__ W2,       // [NLAYERS][HID][HID]
    const float* __restrict__ b2,       // [NLAYERS][HID]
    const float* __restrict__ dts,      // [NLAYERS]
    const float* __restrict__ proj_w,   // [HID][DOUT]
    const float* __restrict__ proj_b,   // [DOUT]
    float* __restrict__ out,            // [B][DOUT]
    int B)
{
    const int tid = blockIdx.x * blockDim.x + threadIdx.x;
    if (tid >= B) return;

    const float x0 = x[3 * tid + 0];
    const float x1 = x[3 * tid + 1];
    const float x2 = x[3 * tid + 2];

    float h[HID];
#pragma unroll
    for (int j = 0; j < HID; ++j) {
        float a = lift_b[j];
        a = fmaf(x0, lift_w[0 * HID + j], a);
        a = fmaf(x1, lift_w[1 * HID + j], a);
        a = fmaf(x2, lift_w[2 * HID + j], a);
        h[j] = a;
    }

    // Layer loop kept rolled (body ~800 FMA fits I$; full unroll would not).
    for (int L = 0; L < NLAYERS; ++L) {
        const float* __restrict__ w1  = W1 + (size_t)L * HID * HID;
        const float* __restrict__ w2  = W2 + (size_t)L * HID * HID;
        const float* __restrict__ bb1 = b1 + (size_t)L * HID;
        const float* __restrict__ bb2 = b2 + (size_t)L * HID;
        const float dt = dts[L];

        float t[HID];
#pragma unroll
        for (int j = 0; j < HID; ++j) t[j] = bb1[j];
#pragma unroll
        for (int k = 0; k < HID; ++k) {
            const float hk = h[k];
#pragma unroll
            for (int j = 0; j < HID; ++j)
                t[j] = fmaf(hk, w1[k * HID + j], t[j]);
        }
#pragma unroll
        for (int j = 0; j < HID; ++j) t[j] = leaky(t[j]);

        float u[HID];
#pragma unroll
        for (int j = 0; j < HID; ++j) u[j] = bb2[j];
#pragma unroll
        for (int k = 0; k < HID; ++k) {
            const float tk = t[k];
#pragma unroll
            for (int j = 0; j < HID; ++j)
                u[j] = fmaf(tk, w2[k * HID + j], u[j]);
        }
#pragma unroll
        for (int j = 0; j < HID; ++j)
            h[j] = fmaf(dt, leaky(u[j]), h[j]);
    }

#pragma unroll
    for (int o = 0; o < DOUT; ++o) {
        float acc = proj_b[o];
#pragma unroll
        for (int k = 0; k < HID; ++k)
            acc = fmaf(h[k], proj_w[k * DOUT + o], acc);
        out[3 * tid + o] = acc;
    }
}

extern "C" void kernel_launch(void* const* d_in, const int* in_sizes, int n_in,
                              void* d_out, int out_size, void* d_ws, size_t ws_size,
                              hipStream_t stream) {
    const float* x      = (const float*)d_in[0];
    const float* lift_w = (const float*)d_in[1];
    const float* lift_b = (const float*)d_in[2];
    const float* W1     = (const float*)d_in[3];
    const float* b1     = (const float*)d_in[4];
    const float* W2     = (const float*)d_in[5];
    const float* b2     = (const float*)d_in[6];
    const float* dts    = (const float*)d_in[7];
    const float* proj_w = (const float*)d_in[8];
    const float* proj_b = (const float*)d_in[9];
    float* out = (float*)d_out;

    const int B = in_sizes[0] / DIN;
    const int block = 256;
    const int grid = (B + block - 1) / block;
    unet_mlp_kernel<<<grid, block, 0, stream>>>(
        x, lift_w, lift_b, W1, b1, W2, b2, dts, proj_w, proj_b, out, B);
}

// Round 2
// 803.616 us; speedup vs baseline: 2.2469x; 2.2469x over previous
//
#include <hip/hip_runtime.h>

// UnstructuredNetwork via fp16 MFMA (v_mfma_f32_32x32x16_f16), fp32 accumulate.
// A = W^T in pre-built fragment layout (prepass kernel -> d_ws), bias folded at k=20.
// B = activations, 32 samples/wave, f16 in wave-private LDS (48 B row stride).
// h residual kept in fp32 registers (C-layout); only MFMA feeds are f16 (RNE).

#define HID 20
#define NLAYERS 50
#define NEG 0.01f

typedef _Float16 half8  __attribute__((ext_vector_type(8)));
typedef _Float16 half2v __attribute__((ext_vector_type(2)));
typedef float    floatx16 __attribute__((ext_vector_type(16)));

__device__ __forceinline__ float leaky(float z) { return fmaxf(z, NEG * z); }

__device__ __forceinline__ unsigned pack2(float a, float b) {
    half2v p;
    p[0] = (_Float16)a;   // v_cvt_f16_f32 (RNE)
    p[1] = (_Float16)b;
    return __builtin_bit_cast(unsigned, p);
}

// ---------------- prepass: build A-operand fragments -----------------------
// A[m][k] for t = W^T(+b) @ act:  A[m][k] = W[k][m] (k<20), A[m][20] = b[m], else 0.
// Fragment: lane l holds m = l&31, k = 16*kstep + 8*(l>>5) + j  (j = 0..7).
// ws layout: wf[((L*2 + matmul)*2 + kstep)*64 + lane] : half8
__global__ void build_wfrags(const float* __restrict__ W1, const float* __restrict__ b1,
                             const float* __restrict__ W2, const float* __restrict__ b2,
                             half8* __restrict__ wf)
{
    const int L = blockIdx.x;
    const int l = threadIdx.x;           // 0..63
    const int m = l & 31, hh = l >> 5;
    const float* Ws[2] = { W1 + L * HID * HID, W2 + L * HID * HID };
    const float* bs[2] = { b1 + L * HID,       b2 + L * HID };
#pragma unroll
    for (int mk = 0; mk < 2; ++mk) {
#pragma unroll
        for (int ks = 0; ks < 2; ++ks) {
            half8 frag;
#pragma unroll
            for (int j = 0; j < 8; ++j) {
                int k = ks * 16 + hh * 8 + j;
                float v = 0.0f;
                if (m < HID) {
                    if (k < HID) v = Ws[mk][k * HID + m];
                    else if (k == HID) v = bs[mk][m];
                }
                frag[j] = (_Float16)v;
            }
            wf[((L * 2 + mk) * 2 + ks) * 64 + l] = frag;
        }
    }
}

// ---------------- main kernel ----------------------------------------------
// Wave-private LDS region (3088 B): hbuf [0,1536), tbuf [1536,3072), zeros [3072,3088).
// Row (sample n): 48 B = 24 f16: k 0..19 = features, k20 = 1.0 (bias mult), k21..23 = 0.
// B-frag reads: kstep1 @ n*48 + 16*hh ; kstep2 @ n*48+32 (hh0) / zero block (hh1).
// C-layout regs r=0..11 <-> rows (r&3)+8*(r>>2)+4*hh (rows 20..23 of half1 unused).
__global__ __launch_bounds__(256) void unet_mfma(
    const float* __restrict__ x,
    const float* __restrict__ lift_w,
    const float* __restrict__ lift_b,
    const float* __restrict__ dts,
    const float* __restrict__ proj_w,
    const float* __restrict__ proj_b,
    const half8* __restrict__ wf,
    float* __restrict__ out, int Bn)
{
    __shared__ __align__(16) unsigned char lds[4 * 3088];
    const int tid = threadIdx.x;
    const int wv  = tid >> 6;
    const int l   = tid & 63;
    const int n   = l & 31;
    const int hh  = l >> 5;

    unsigned char* wl = lds + wv * 3088;
    if (l < 4) ((unsigned*)(wl + 3072))[l] = 0u;   // zero block (same-wave DS order)

    unsigned char* waddr       = wl + n * 48 + hh * 8;    // write base (half1 = +8)
    const unsigned char* rd1   = wl + n * 48 + hh * 16;   // kstep1 read
    const unsigned char* rd2h  = hh ? (wl + 3072) : (wl + n * 48 + 32);
    const unsigned char* rd2t  = hh ? (wl + 3072) : (wl + n * 48 + 32 + 1536);

    const int g  = blockIdx.x * 128 + wv * 32 + n;
    const int gi = g < Bn ? g : Bn - 1;

    const float x0 = x[3 * gi + 0];
    const float x1 = x[3 * gi + 1];
    const float x2 = x[3 * gi + 2];

    // lift -> h (fp32, C-layout registers)
    float h[12];
#pragma unroll
    for (int r = 0; r < 12; ++r) {
        const int row = (r & 3) + 8 * (r >> 2) + 4 * hh;
        float a = lift_b[row];
        a = fmaf(x0, lift_w[0 * HID + row], a);
        a = fmaf(x1, lift_w[1 * HID + row], a);
        a = fmaf(x2, lift_w[2 * HID + row], a);
        h[r] = a;
    }

    // write h -> hbuf (f16)
    {
        const unsigned p4 = hh ? 0x00003C00u : pack2(h[8], h[9]);    // (1.0, 0) for half1
        const unsigned p5 = hh ? 0u          : pack2(h[10], h[11]);
        *(unsigned*)(waddr + 0)  = pack2(h[0], h[1]);
        *(unsigned*)(waddr + 4)  = pack2(h[2], h[3]);
        *(unsigned*)(waddr + 16) = pack2(h[4], h[5]);
        *(unsigned*)(waddr + 20) = pack2(h[6], h[7]);
        *(unsigned*)(waddr + 32) = p4;
        *(unsigned*)(waddr + 36) = p5;
    }
    __asm__ volatile("" ::: "memory");

    const half8* wfl = wf + l;
    const floatx16 zf = {0,0,0,0,0,0,0,0,0,0,0,0,0,0,0,0};

    for (int L = 0; L < NLAYERS; ++L) {
        const float dt = dts[L];
        const half8 a10 = wfl[(L * 4 + 0) * 64];
        const half8 a11 = wfl[(L * 4 + 1) * 64];
        const half8 a20 = wfl[(L * 4 + 2) * 64];
        const half8 a21 = wfl[(L * 4 + 3) * 64];

        // matmul1: t = W1^T(+b1) @ h
        const half8 b0 = *(const half8*)rd1;
        const half8 b1 = *(const half8*)rd2h;
        floatx16 acc = zf;
        acc = __builtin_amdgcn_mfma_f32_32x32x16_f16(a10, b0, acc, 0, 0, 0);
        acc = __builtin_amdgcn_mfma_f32_32x32x16_f16(a11, b1, acc, 0, 0, 0);

        float t[12];
#pragma unroll
        for (int r = 0; r < 12; ++r) t[r] = leaky(acc[r]);

        {
            const unsigned p4 = hh ? 0x00003C00u : pack2(t[8], t[9]);
            const unsigned p5 = hh ? 0u          : pack2(t[10], t[11]);
            *(unsigned*)(waddr + 1536 + 0)  = pack2(t[0], t[1]);
            *(unsigned*)(waddr + 1536 + 4)  = pack2(t[2], t[3]);
            *(unsigned*)(waddr + 1536 + 16) = pack2(t[4], t[5]);
            *(unsigned*)(waddr + 1536 + 20) = pack2(t[6], t[7]);
            *(unsigned*)(waddr + 1536 + 32) = p4;
            *(unsigned*)(waddr + 1536 + 36) = p5;
        }
        __asm__ volatile("" ::: "memory");

        // matmul2: u = W2^T(+b2) @ t
        const half8 c0 = *(const half8*)(rd1 + 1536);
        const half8 c1 = *(const half8*)rd2t;
        floatx16 acc2 = zf;
        acc2 = __builtin_amdgcn_mfma_f32_32x32x16_f16(a20, c0, acc2, 0, 0, 0);
        acc2 = __builtin_amdgcn_mfma_f32_32x32x16_f16(a21, c1, acc2, 0, 0, 0);

#pragma unroll
        for (int r = 0; r < 12; ++r) h[r] = fmaf(dt, leaky(acc2[r]), h[r]);

        // write h -> hbuf for next layer
        {
            const unsigned p4 = hh ? 0x00003C00u : pack2(h[8], h[9]);
            const unsigned p5 = hh ? 0u          : pack2(h[10], h[11]);
            *(unsigned*)(waddr + 0)  = pack2(h[0], h[1]);
            *(unsigned*)(waddr + 4)  = pack2(h[2], h[3]);
            *(unsigned*)(waddr + 16) = pack2(h[4], h[5]);
            *(unsigned*)(waddr + 20) = pack2(h[6], h[7]);
            *(unsigned*)(waddr + 32) = p4;
            *(unsigned*)(waddr + 36) = p5;
        }
        __asm__ volatile("" ::: "memory");
    }

    // projection from fp32 h regs; lanes l and l^32 hold complementary rows
    float po0 = 0.f, po1 = 0.f, po2 = 0.f;
#pragma unroll
    for (int r = 0; r < 12; ++r) {
        const int row  = (r & 3) + 8 * (r >> 2) + 4 * hh;
        const float hv = (row < HID) ? h[r] : 0.0f;
        const int rowc = (row < HID) ? row : 0;
        po0 = fmaf(hv, proj_w[rowc * 3 + 0], po0);
        po1 = fmaf(hv, proj_w[rowc * 3 + 1], po1);
        po2 = fmaf(hv, proj_w[rowc * 3 + 2], po2);
    }
    po0 += __shfl_xor(po0, 32, 64);
    po1 += __shfl_xor(po1, 32, 64);
    po2 += __shfl_xor(po2, 32, 64);
    if (hh == 0 && g < Bn) {
        out[3 * g + 0] = po0 + proj_b[0];
        out[3 * g + 1] = po1 + proj_b[1];
        out[3 * g + 2] = po2 + proj_b[2];
    }
}

extern "C" void kernel_launch(void* const* d_in, const int* in_sizes, int n_in,
                              void* d_out, int out_size, void* d_ws, size_t ws_size,
                              hipStream_t stream) {
    const float* x      = (const float*)d_in[0];
    const float* lift_w = (const float*)d_in[1];
    const float* lift_b = (const float*)d_in[2];
    const float* W1     = (const float*)d_in[3];
    const float* b1     = (const float*)d_in[4];
    const float* W2     = (const float*)d_in[5];
    const float* b2     = (const float*)d_in[6];
    const float* dts    = (const float*)d_in[7];
    const float* proj_w = (const float*)d_in[8];
    const float* proj_b = (const float*)d_in[9];
    float* out = (float*)d_out;

    const int B = in_sizes[0] / 3;
    half8* wf = (half8*)d_ws;   // NLAYERS*4*64*16 B = 200 KiB

    build_wfrags<<<NLAYERS, 64, 0, stream>>>(W1, b1, W2, b2, wf);

    const int blocks = (B + 127) / 128;   // 128 samples/block (4 waves x 32)
    unet_mfma<<<blocks, 256, 0, stream>>>(
        x, lift_w, lift_b, dts, proj_w, proj_b, wf, out, B);
}

// Round 3
// 656.429 us; speedup vs baseline: 2.7507x; 1.2242x over previous
//
#include <hip/hip_runtime.h>

// UnstructuredNetwork via fp16 MFMA (v_mfma_f32_32x32x16_f16), fp32 accumulate.
// R3: VALU-issue-bound fix — pkrtz+packed-f16 leaky for t-feed, b64 LDS writes
// (bank-tiled), no zero-block (kstep2 junk columns hit zero A-weights), hoisted
// zero-C, launch_bounds(256,4) to keep accumulators in VGPRs.
// h residual stays fp32 in registers (C-layout); h-feed packs stay RNE.

#define HID 20
#define NLAYERS 50
#define NEG 0.01f

typedef _Float16 half8   __attribute__((ext_vector_type(8)));
typedef _Float16 half2v  __attribute__((ext_vector_type(2)));
typedef __fp16   fp16x2  __attribute__((ext_vector_type(2)));
typedef float    floatx16 __attribute__((ext_vector_type(16)));
typedef unsigned uint2v  __attribute__((ext_vector_type(2)));

__device__ __forceinline__ unsigned pack_rne(float a, float b) {
    half2v p;
    p[0] = (_Float16)a;   // v_cvt_f16_f32 (RNE)
    p[1] = (_Float16)b;
    return __builtin_bit_cast(unsigned, p);
}

// ---------------- prepass: build A-operand fragments -----------------------
// A[m][k]: A[m][k] = W[k][m] (k<20), A[m][20] = b[m], else 0 (incl. all k>=21,
// and all rows m>=20). Lane l holds m=l&31, k = 16*ks + 8*(l>>5) + j (j=0..7).
// ws layout: wf[(L*4 + mk*2 + ks)*64 + lane] : half8
__global__ void build_wfrags(const float* __restrict__ W1, const float* __restrict__ b1,
                             const float* __restrict__ W2, const float* __restrict__ b2,
                             half8* __restrict__ wf)
{
    const int L = blockIdx.x;
    const int l = threadIdx.x;           // 0..63
    const int m = l & 31, hh = l >> 5;
    const float* Ws[2] = { W1 + L * HID * HID, W2 + L * HID * HID };
    const float* bs[2] = { b1 + L * HID,       b2 + L * HID };
#pragma unroll
    for (int mk = 0; mk < 2; ++mk) {
#pragma unroll
        for (int ks = 0; ks < 2; ++ks) {
            half8 frag;
#pragma unroll
            for (int j = 0; j < 8; ++j) {
                int k = ks * 16 + hh * 8 + j;
                float v = 0.0f;
                if (m < HID) {
                    if (k < HID) v = Ws[mk][k * HID + m];
                    else if (k == HID) v = bs[mk][m];
                }
                frag[j] = (_Float16)v;
            }
            wf[((L * 2 + mk) * 2 + ks) * 64 + l] = frag;
        }
    }
}

// ---------------- main kernel ----------------------------------------------
// Wave-private LDS (3072 B): hbuf [0,1536), tbuf [1536,3072).
// Row (sample n, 48 B): k0..19 features, k20 = 1.0 (bias mult), k21..23 = 0.
// Writes: hh=0 lane -> b64 at +0 (rows0-3), +16 (rows8-11), +32 (rows16-19);
//         hh=1 lane -> b64 at +8 (rows4-7), +24 (rows12-15), +40 (const 1.0,0,0,0).
// Reads:  kstep1 b128 @ n*48+16*hh (k0-15); kstep2 b128 @ n*48+32 (both halves;
//         hh=1's k24-31 slots multiply zero A-columns, junk is harmless).
__global__ __launch_bounds__(256, 4) void unet_mfma(
    const float* __restrict__ x,
    const float* __restrict__ lift_w,
    const float* __restrict__ lift_b,
    const float* __restrict__ dts,
    const float* __restrict__ proj_w,
    const float* __restrict__ proj_b,
    const half8* __restrict__ wf,
    float* __restrict__ out, int Bn)
{
    __shared__ __align__(16) unsigned char lds[4 * 3072];
    const int tid = threadIdx.x;
    const int wv  = tid >> 6;
    const int l   = tid & 63;
    const int n   = l & 31;
    const int hh  = l >> 5;

    unsigned char* wl = lds + wv * 3072;
    unsigned char* waddr       = wl + n * 48 + hh * 8;    // write base
    const unsigned char* rd1   = wl + n * 48 + hh * 16;   // kstep1 read
    const unsigned char* rd2   = wl + n * 48 + 32;        // kstep2 read (both halves)

    const int g  = blockIdx.x * 128 + wv * 32 + n;
    const int gi = g < Bn ? g : Bn - 1;

    const float x0 = x[3 * gi + 0];
    const float x1 = x[3 * gi + 1];
    const float x2 = x[3 * gi + 2];

    // lift -> h (fp32, C-layout registers); rows >= HID forced to 0
    float h[12];
#pragma unroll
    for (int r = 0; r < 12; ++r) {
        const int row = (r & 3) + 8 * (r >> 2) + 4 * hh;
        if (row < HID) {
            float a = lift_b[row];
            a = fmaf(x0, lift_w[0 * HID + row], a);
            a = fmaf(x1, lift_w[1 * HID + row], a);
            a = fmaf(x2, lift_w[2 * HID + row], a);
            h[r] = a;
        } else {
            h[r] = 0.0f;
        }
    }

    const unsigned C10 = 0x00003C00u;   // f16 (1.0, 0.0) packed

    // initial h -> hbuf
    {
        const unsigned p0 = pack_rne(h[0], h[1]);
        const unsigned p1 = pack_rne(h[2], h[3]);
        const unsigned p2 = pack_rne(h[4], h[5]);
        const unsigned p3 = pack_rne(h[6], h[7]);
        const unsigned p4 = hh ? C10 : pack_rne(h[8], h[9]);
        const unsigned p5 = hh ? 0u  : pack_rne(h[10], h[11]);
        *(uint2v*)(waddr + 0)  = (uint2v){p0, p1};
        *(uint2v*)(waddr + 16) = (uint2v){p2, p3};
        *(uint2v*)(waddr + 32) = (uint2v){p4, p5};
    }
    __asm__ volatile("" ::: "memory");

    const half8* wfl = wf + l;
    floatx16 zf;
#pragma unroll
    for (int i = 0; i < 16; ++i) zf[i] = 0.0f;

    const fp16x2 negs = {(__fp16)NEG, (__fp16)NEG};

    for (int L = 0; L < NLAYERS; ++L) {
        const float dt = dts[L];
        const half8 a10 = wfl[(L * 4 + 0) * 64];
        const half8 a11 = wfl[(L * 4 + 1) * 64];
        const half8 a20 = wfl[(L * 4 + 2) * 64];
        const half8 a21 = wfl[(L * 4 + 3) * 64];

        // matmul1: t = W1^T(+b1) @ h   (C = hoisted zeros)
        const half8 b0 = *(const half8*)rd1;
        const half8 b1 = *(const half8*)rd2;
        floatx16 acc = __builtin_amdgcn_mfma_f32_32x32x16_f16(a10, b0, zf, 0, 0, 0);
        acc = __builtin_amdgcn_mfma_f32_32x32x16_f16(a11, b1, acc, 0, 0, 0);

        // t-feed: pkrtz then packed-f16 leaky (within-layer intermediate; RTZ ok)
        unsigned tp[6];
#pragma unroll
        for (int i = 0; i < 6; ++i) {
            fp16x2 z  = __builtin_amdgcn_cvt_pkrtz(acc[2 * i], acc[2 * i + 1]);
            fp16x2 t2 = __builtin_elementwise_max(z, z * negs);
            tp[i] = __builtin_bit_cast(unsigned, t2);
        }
        {
            const unsigned w4 = hh ? C10 : tp[4];
            const unsigned w5 = hh ? 0u  : tp[5];
            *(uint2v*)(waddr + 1536 + 0)  = (uint2v){tp[0], tp[1]};
            *(uint2v*)(waddr + 1536 + 16) = (uint2v){tp[2], tp[3]};
            *(uint2v*)(waddr + 1536 + 32) = (uint2v){w4, w5};
        }
        __asm__ volatile("" ::: "memory");

        // matmul2: u = W2^T(+b2) @ t
        const half8 c0 = *(const half8*)(rd1 + 1536);
        const half8 c1 = *(const half8*)(rd2 + 1536);
        floatx16 acc2 = __builtin_amdgcn_mfma_f32_32x32x16_f16(a20, c0, zf, 0, 0, 0);
        acc2 = __builtin_amdgcn_mfma_f32_32x32x16_f16(a21, c1, acc2, 0, 0, 0);

        // residual update in fp32
#pragma unroll
        for (int r = 0; r < 12; ++r) {
            const float z = acc2[r];
            h[r] = fmaf(dt, fmaxf(z, NEG * z), h[r]);
        }

        // h -> hbuf (RNE packs: residual stream feeds all later layers)
        {
            const unsigned p0 = pack_rne(h[0], h[1]);
            const unsigned p1 = pack_rne(h[2], h[3]);
            const unsigned p2 = pack_rne(h[4], h[5]);
            const unsigned p3 = pack_rne(h[6], h[7]);
            const unsigned p4 = hh ? C10 : pack_rne(h[8], h[9]);
            const unsigned p5 = hh ? 0u  : pack_rne(h[10], h[11]);
            *(uint2v*)(waddr + 0)  = (uint2v){p0, p1};
            *(uint2v*)(waddr + 16) = (uint2v){p2, p3};
            *(uint2v*)(waddr + 32) = (uint2v){p4, p5};
        }
        __asm__ volatile("" ::: "memory");
    }

    // projection from fp32 h regs; lanes l and l^32 hold complementary rows
    float po0 = 0.f, po1 = 0.f, po2 = 0.f;
#pragma unroll
    for (int r = 0; r < 12; ++r) {
        const int row  = (r & 3) + 8 * (r >> 2) + 4 * hh;
        const float hv = (row < HID) ? h[r] : 0.0f;
        const int rowc = (row < HID) ? row : 0;
        po0 = fmaf(hv, proj_w[rowc * 3 + 0], po0);
        po1 = fmaf(hv, proj_w[rowc * 3 + 1], po1);
        po2 = fmaf(hv, proj_w[rowc * 3 + 2], po2);
    }
    po0 += __shfl_xor(po0, 32, 64);
    po1 += __shfl_xor(po1, 32, 64);
    po2 += __shfl_xor(po2, 32, 64);
    if (hh == 0 && g < Bn) {
        out[3 * g + 0] = po0 + proj_b[0];
        out[3 * g + 1] = po1 + proj_b[1];
        out[3 * g + 2] = po2 + proj_b[2];
    }
}

extern "C" void kernel_launch(void* const* d_in, const int* in_sizes, int n_in,
                              void* d_out, int out_size, void* d_ws, size_t ws_size,
                              hipStream_t stream) {
    const float* x      = (const float*)d_in[0];
    const float* lift_w = (const float*)d_in[1];
    const float* lift_b = (const float*)d_in[2];
    const float* W1     = (const float*)d_in[3];
    const float* b1     = (const float*)d_in[4];
    const float* W2     = (const float*)d_in[5];
    const float* b2     = (const float*)d_in[6];
    const float* dts    = (const float*)d_in[7];
    const float* proj_w = (const float*)d_in[8];
    const float* proj_b = (const float*)d_in[9];
    float* out = (float*)d_out;

    const int B = in_sizes[0] / 3;
    half8* wf = (half8*)d_ws;   // NLAYERS*4*64*16 B = 200 KiB

    build_wfrags<<<NLAYERS, 64, 0, stream>>>(W1, b1, W2, b2, wf);

    const int blocks = (B + 127) / 128;   // 128 samples/block (4 waves x 32)
    unet_mfma<<<blocks, 256, 0, stream>>>(
        x, lift_w, lift_b, dts, proj_w, proj_b, wf, out, B);
}